// Round 10
// baseline (475.751 us; speedup 1.0000x reference)
//
#include <hip/hip_runtime.h>

// VectorQuantizer: z[32,32,64,64] f32 (BCHW), emb[1024,32] f32.
// out = concat( z_q[32,32,64,64] f32 , idx[131072] stored as f32 values ).
//
// R10: single-scan MFMA filter with chunked LDS staging (256-code chunks,
// 37 KB -> 4 blocks/CU = 4 waves/SIMD; R9's 151 KB gave 1 wave/SIMD and
// died of latency). Per-lane (min1,idx1,min2) tracking replaces the second
// flag pass: after the 16-lane butterfly min, min1<=m*+margin flags idx1;
// min2<=m*+margin forces a full exact rescan of that query (safe superset).
// A-fragments built directly from z (bf16 hi/lo split in-register, same bits
// as the old prep_z). pass3 exact-rescores candidates with the verified
// numpy-fp32 chain (first-index ties via u64 (d,idx) key).

#define NUM_EMB 1024
#define EMB_DIM 32
#define HW      4096
#define BATCH   32
#define N_TOT   (BATCH * HW)  // 131072
#define NSPLIT  4
#define CODES_PER (NUM_EMB / NSPLIT)
#define MARGIN  2.0e-4f
#define CHUNK   256
#define ESTRIDE 36            // LDS row stride in shorts (bank-conflict pad)

// ws layout
#define OFF_BQ   0u
#define OFF_EH   4096u
#define OFF_EL   69632u
#define OFF_CNT  135168u
#define OFF_CAND 659456u
#define WS_NEED  4853760u
#define WS_NEED_R7 (4096u + 4u * 131072u * 8u)

using bf16x8 = __attribute__((ext_vector_type(8))) short;
using bf16x4 = __attribute__((ext_vector_type(4))) short;
using f32x4  = __attribute__((ext_vector_type(4))) float;

#define REPEAT32(M) \
    M(0)  M(1)  M(2)  M(3)  M(4)  M(5)  M(6)  M(7)  \
    M(8)  M(9)  M(10) M(11) M(12) M(13) M(14) M(15) \
    M(16) M(17) M(18) M(19) M(20) M(21) M(22) M(23) \
    M(24) M(25) M(26) M(27) M(28) M(29) M(30) M(31)

__device__ __forceinline__ unsigned short bf16_rne(float x) {
    unsigned u = __float_as_uint(x);
    return (unsigned short)((u + 0x7FFFu + ((u >> 16) & 1u)) >> 16);
}

__device__ __forceinline__ float pairwise_sq32(const float* __restrict__ e) {
    float r0 = __fmul_rn(e[0], e[0]), r1 = __fmul_rn(e[1], e[1]);
    float r2 = __fmul_rn(e[2], e[2]), r3 = __fmul_rn(e[3], e[3]);
    float r4 = __fmul_rn(e[4], e[4]), r5 = __fmul_rn(e[5], e[5]);
    float r6 = __fmul_rn(e[6], e[6]), r7 = __fmul_rn(e[7], e[7]);
#pragma unroll
    for (int i = 8; i < 32; i += 8) {
        r0 = __fadd_rn(r0, __fmul_rn(e[i + 0], e[i + 0]));
        r1 = __fadd_rn(r1, __fmul_rn(e[i + 1], e[i + 1]));
        r2 = __fadd_rn(r2, __fmul_rn(e[i + 2], e[i + 2]));
        r3 = __fadd_rn(r3, __fmul_rn(e[i + 3], e[i + 3]));
        r4 = __fadd_rn(r4, __fmul_rn(e[i + 4], e[i + 4]));
        r5 = __fadd_rn(r5, __fmul_rn(e[i + 5], e[i + 5]));
        r6 = __fadd_rn(r6, __fmul_rn(e[i + 6], e[i + 6]));
        r7 = __fadd_rn(r7, __fmul_rn(e[i + 7], e[i + 7]));
    }
    return __fadd_rn(__fadd_rn(__fadd_rn(r0, r1), __fadd_rn(r2, r3)),
                     __fadd_rn(__fadd_rn(r4, r5), __fadd_rn(r6, r7)));
}

__device__ __forceinline__ void store_row16(unsigned short* dst,
                                            const unsigned short* v) {
    unsigned w[16];
#pragma unroll
    for (int i = 0; i < 16; ++i)
        w[i] = (unsigned)v[2 * i] | ((unsigned)v[2 * i + 1] << 16);
    uint4* d4 = (uint4*)dst;
    d4[0] = make_uint4(w[0], w[1], w[2], w[3]);
    d4[1] = make_uint4(w[4], w[5], w[6], w[7]);
    d4[2] = make_uint4(w[8], w[9], w[10], w[11]);
    d4[3] = make_uint4(w[12], w[13], w[14], w[15]);
}

// ---- prep_e: bq exact + eh/el bf16 split ----------------------------------
__global__ __launch_bounds__(256) void vq_prep_e(
        const float* __restrict__ emb, float* __restrict__ bq,
        unsigned short* __restrict__ eh, unsigned short* __restrict__ el) {
    const int j = blockIdx.x * 256 + threadIdx.x;
    if (j >= NUM_EMB) return;
    const float* e = emb + j * EMB_DIM;
    bq[j] = pairwise_sq32(e);
    unsigned short h[32], l[32];
#pragma unroll
    for (int c = 0; c < 32; ++c) {
        float v = e[c];
        unsigned short hb = bf16_rne(v);
        float hf = __uint_as_float((unsigned)hb << 16);
        l[c] = bf16_rne(v - hf);
        h[c] = hb;
    }
    store_row16(eh + (size_t)j * 32, h);
    store_row16(el + (size_t)j * 32, l);
}

__device__ __forceinline__ bf16x8 lds_read8(const short* p) {
    bf16x4 a = *(const bf16x4*)p;        // 8B-aligned ds_read_b64
    bf16x4 b = *(const bf16x4*)(p + 4);
    return __builtin_shufflevector(a, b, 0, 1, 2, 3, 4, 5, 6, 7);
}

// ---- fused filter ---------------------------------------------------------
// Block = 256 thr = 4 waves; block handles 256 queries (wave: 64).
// Codebook scanned in 4 chunks of 256 codes staged in LDS (37 KB).
// A frag: A[m=cloc][k=quad*8+e] from z (bf16 split in-reg).
// B frag: B[k][n=cloc] from LDS. D: query row = quad*4+r, code col = cloc.
__global__ __launch_bounds__(256, 4) void vq_filter(
        const float* __restrict__ z,
        const unsigned short* __restrict__ eh,
        const unsigned short* __restrict__ el,
        const float* __restrict__ bq, int* __restrict__ cnt,
        int* __restrict__ cand) {
    __shared__ __align__(16) short seh[CHUNK * ESTRIDE];
    __shared__ __align__(16) short sel[CHUNK * ESTRIDE];
    __shared__ float sbq[CHUNK];

    const int tid  = threadIdx.x;
    const int lane = tid & 63;
    const int wv   = tid >> 6;
    const int cloc = lane & 15, quad = lane >> 4;
    const int qbase = blockIdx.x * 256 + wv * 64;

    // A-fragments straight from z, bf16 hi/lo split (same bits as prep_z did)
    bf16x8 azh[4], azl[4];
#pragma unroll
    for (int t = 0; t < 4; ++t) {
        const int q  = qbase + t * 16 + cloc;
        const int b  = q >> 12;
        const int hw = q & 4095;
        const float* zb = z + ((size_t)b * EMB_DIM + quad * 8) * HW + hw;
#pragma unroll
        for (int k = 0; k < 8; ++k) {
            float v = zb[(size_t)k * HW];
            unsigned short hb = bf16_rne(v);
            float hf = __uint_as_float((unsigned)hb << 16);
            azh[t][k] = (short)hb;
            azl[t][k] = (short)bf16_rne(v - hf);
        }
    }

    float m1[4][4], m2[4][4];
    int   i1[4][4];
#pragma unroll
    for (int t = 0; t < 4; ++t)
#pragma unroll
        for (int r = 0; r < 4; ++r) {
            m1[t][r] = 3.4e38f; m2[t][r] = 3.4e38f; i1[t][r] = 0;
        }

    for (int ch = 0; ch < 4; ++ch) {
        if (ch) __syncthreads();   // all waves done with previous chunk
        // stage 256 codes: 1024 8B-chunks per array, 4 per thread
#pragma unroll
        for (int i = 0; i < 4; ++i) {
            const int chunk = i * 256 + tid;      // 0..1023
            const int r = chunk >> 2, c = chunk & 3;
            *(uint2*)&seh[r * ESTRIDE + c * 8] =
                *(const uint2*)(eh + (size_t)(ch * CHUNK + r) * 32 + c * 8);
            *(uint2*)&sel[r * ESTRIDE + c * 8] =
                *(const uint2*)(el + (size_t)(ch * CHUNK + r) * 32 + c * 8);
        }
        sbq[tid] = bq[ch * CHUNK + tid];
        __syncthreads();

        for (int jt = 0; jt < 16; ++jt) {
            const int row = jt * 16 + cloc;
            bf16x8 efh = lds_read8(&seh[row * ESTRIDE + quad * 8]);
            bf16x8 efl = lds_read8(&sel[row * ESTRIDE + quad * 8]);
            const float bqv = sbq[row];
            const int jts = ch * 16 + jt;         // wave-uniform
#pragma unroll
            for (int t = 0; t < 4; ++t) {
                f32x4 acc = {0.f, 0.f, 0.f, 0.f};
                acc = __builtin_amdgcn_mfma_f32_16x16x32_bf16(azl[t], efh, acc, 0, 0, 0);
                acc = __builtin_amdgcn_mfma_f32_16x16x32_bf16(azh[t], efl, acc, 0, 0, 0);
                acc = __builtin_amdgcn_mfma_f32_16x16x32_bf16(azh[t], efh, acc, 0, 0, 0);
#pragma unroll
                for (int r = 0; r < 4; ++r) {
                    float tt = __fmaf_rn(-2.0f, acc[r], bqv);
                    bool lt = tt < m1[t][r];
                    m2[t][r] = fminf(m2[t][r], fmaxf(tt, m1[t][r]));
                    m1[t][r] = fminf(m1[t][r], tt);
                    i1[t][r] = lt ? jts : i1[t][r];
                }
            }
        }
    }

    // global min per query across the 16 cloc lanes
    float g[4][4];
#pragma unroll
    for (int t = 0; t < 4; ++t)
#pragma unroll
        for (int r = 0; r < 4; ++r) g[t][r] = m1[t][r];
#pragma unroll
    for (int off = 1; off < 16; off <<= 1)
#pragma unroll
        for (int t = 0; t < 4; ++t)
#pragma unroll
            for (int r = 0; r < 4; ++r)
                g[t][r] = fminf(g[t][r], __shfl_xor(g[t][r], off, 64));

    // flag candidates; min2 within margin -> force full rescan (safe)
#pragma unroll
    for (int t = 0; t < 4; ++t)
#pragma unroll
        for (int r = 0; r < 4; ++r) {
            const float thr = g[t][r] + MARGIN;
            const int q = qbase + t * 16 + quad * 4 + r;
            if (m1[t][r] <= thr) {
                int pos = atomicAdd(&cnt[q], 1);
                if (pos < 8) cand[(q << 3) + pos] = i1[t][r] * 16 + cloc;
            }
            if (m2[t][r] <= thr) atomicAdd(&cnt[q], 1000);
        }
}

// ---- pass3: exact rescore of candidates, write idx + z_q ------------------
#define LOADZ(c) float z##c = zp[(size_t)(c) * HW];
#define Z_SQ_A()                                                              \
    float r0 = __fmul_rn(z0, z0), r1 = __fmul_rn(z1, z1);                     \
    float r2 = __fmul_rn(z2, z2), r3 = __fmul_rn(z3, z3);                     \
    float r4 = __fmul_rn(z4, z4), r5 = __fmul_rn(z5, z5);                     \
    float r6 = __fmul_rn(z6, z6), r7 = __fmul_rn(z7, z7);                     \
    r0 = __fadd_rn(r0, __fmul_rn(z8,  z8));  r0 = __fadd_rn(r0, __fmul_rn(z16, z16)); \
    r0 = __fadd_rn(r0, __fmul_rn(z24, z24));                                  \
    r1 = __fadd_rn(r1, __fmul_rn(z9,  z9));  r1 = __fadd_rn(r1, __fmul_rn(z17, z17)); \
    r1 = __fadd_rn(r1, __fmul_rn(z25, z25));                                  \
    r2 = __fadd_rn(r2, __fmul_rn(z10, z10)); r2 = __fadd_rn(r2, __fmul_rn(z18, z18)); \
    r2 = __fadd_rn(r2, __fmul_rn(z26, z26));                                  \
    r3 = __fadd_rn(r3, __fmul_rn(z11, z11)); r3 = __fadd_rn(r3, __fmul_rn(z19, z19)); \
    r3 = __fadd_rn(r3, __fmul_rn(z27, z27));                                  \
    r4 = __fadd_rn(r4, __fmul_rn(z12, z12)); r4 = __fadd_rn(r4, __fmul_rn(z20, z20)); \
    r4 = __fadd_rn(r4, __fmul_rn(z28, z28));                                  \
    r5 = __fadd_rn(r5, __fmul_rn(z13, z13)); r5 = __fadd_rn(r5, __fmul_rn(z21, z21)); \
    r5 = __fadd_rn(r5, __fmul_rn(z29, z29));                                  \
    r6 = __fadd_rn(r6, __fmul_rn(z14, z14)); r6 = __fadd_rn(r6, __fmul_rn(z22, z22)); \
    r6 = __fadd_rn(r6, __fmul_rn(z30, z30));                                  \
    r7 = __fadd_rn(r7, __fmul_rn(z15, z15)); r7 = __fadd_rn(r7, __fmul_rn(z23, z23)); \
    r7 = __fadd_rn(r7, __fmul_rn(z31, z31));                                  \
    const float a = __fadd_rn(                                                \
        __fadd_rn(__fadd_rn(r0, r1), __fadd_rn(r2, r3)),                      \
        __fadd_rn(__fadd_rn(r4, r5), __fadd_rn(r6, r7)));

#define FMA1(k) m = __fmaf_rn(z##k, e[(k)], m);
#define EXACT_KEY(jv)                                                         \
    {                                                                         \
        const float* e = emb + (size_t)(jv) * EMB_DIM;                        \
        float m = 0.0f;                                                       \
        REPEAT32(FMA1)                                                        \
        float d = __fsub_rn(__fadd_rn(a, bq[(jv)]), __fmul_rn(2.0f, m));      \
        unsigned u = __float_as_uint(d);                                      \
        u = (u & 0x80000000u) ? ~u : (u | 0x80000000u);                       \
        unsigned long long kk =                                               \
            ((unsigned long long)u << 32) | (unsigned)(jv);                   \
        if (kk < bestk) bestk = kk;                                           \
    }

__global__ __launch_bounds__(256, 2) void vq_pass3(
        const float* __restrict__ z, const float* __restrict__ emb,
        const float* __restrict__ bq, const int* __restrict__ cnt,
        const int* __restrict__ cand, float* __restrict__ out_zq,
        float* __restrict__ out_idx) {
    const int n  = blockIdx.x * 256 + threadIdx.x;
    const int b  = n >> 12;
    const int hw = n & 4095;
    const float* zp = z + (size_t)b * EMB_DIM * HW + hw;
    REPEAT32(LOADZ)
    Z_SQ_A()

    const int c = cnt[n];
    unsigned long long bestk = ~0ull;
    if (c >= 1 && c <= 8) {
        for (int i = 0; i < c; ++i) { const int jv = cand[(n << 3) + i]; EXACT_KEY(jv) }
    } else {  // overflow / breakage safety: full exact scan
        for (int jv = 0; jv < NUM_EMB; ++jv) EXACT_KEY(jv)
    }
    const int bidx = (int)(unsigned)(bestk & 0xffffffffu);
    out_idx[n] = (float)bidx;
    const float* eb = emb + (size_t)bidx * EMB_DIM;
    float* op = out_zq + (size_t)b * EMB_DIM * HW + hw;
#pragma unroll
    for (int cc = 0; cc < EMB_DIM; ++cc) op[(size_t)cc * HW] = eb[cc];
}

// ================== proven R7/R5 exhaustive fallback =======================
#define SCAN_GROUP4(j)                                                        \
    {                                                                         \
        const float* e = emb + (size_t)(j) * EMB_DIM;                         \
        const float bq0 = bq[(j) + 0], bq1 = bq[(j) + 1];                     \
        const float bq2 = bq[(j) + 2], bq3 = bq[(j) + 3];                     \
        float m0 = 0.0f, m1 = 0.0f, m2 = 0.0f, m3 = 0.0f;                     \
        REPEAT32(FMA_K)                                                       \
        float d0 = __fsub_rn(__fadd_rn(a, bq0), __fmul_rn(2.0f, m0));         \
        float d1 = __fsub_rn(__fadd_rn(a, bq1), __fmul_rn(2.0f, m1));         \
        float d2 = __fsub_rn(__fadd_rn(a, bq2), __fmul_rn(2.0f, m2));         \
        float d3 = __fsub_rn(__fadd_rn(a, bq3), __fmul_rn(2.0f, m3));         \
        if (d0 < best) { best = d0; bidx = (j) + 0; }                         \
        if (d1 < best) { best = d1; bidx = (j) + 1; }                         \
        if (d2 < best) { best = d2; bidx = (j) + 2; }                         \
        if (d3 < best) { best = d3; bidx = (j) + 3; }                         \
    }
#define FMA_K(k) \
        m0 = __fmaf_rn(z##k, e[0 * EMB_DIM + (k)], m0); \
        m1 = __fmaf_rn(z##k, e[1 * EMB_DIM + (k)], m1); \
        m2 = __fmaf_rn(z##k, e[2 * EMB_DIM + (k)], m2); \
        m3 = __fmaf_rn(z##k, e[3 * EMB_DIM + (k)], m3);

__global__ __launch_bounds__(256) void vq_sqnorm_kernel(
        const float* __restrict__ emb, float* __restrict__ bq) {
    int j = blockIdx.x * 256 + threadIdx.x;
    if (j < NUM_EMB) bq[j] = pairwise_sq32(emb + j * EMB_DIM);
}

__global__ __launch_bounds__(128, 4) void vq_partial_kernel(
        const float* __restrict__ z, const float* __restrict__ emb,
        const float* __restrict__ bq, unsigned long long* __restrict__ pk) {
    const int n  = blockIdx.x * 128 + threadIdx.x;
    const int b  = n >> 12;
    const int hw = n & 4095;
    const float* zp = z + (size_t)b * EMB_DIM * HW + hw;
    REPEAT32(LOADZ)
    Z_SQ_A()
    const int j0 = blockIdx.y * CODES_PER;
    float best = 3.4e38f;
    int   bidx = j0;
    for (int j = j0; j < j0 + CODES_PER; j += 4) SCAN_GROUP4(j)
    pk[(size_t)blockIdx.y * N_TOT + n] =
        ((unsigned long long)__float_as_uint(best) << 32) | (unsigned)bidx;
}

__global__ __launch_bounds__(256, 2) void vq_main_kernel(
        const float* __restrict__ z, const float* __restrict__ emb,
        const float* __restrict__ bq, float* __restrict__ out_zq,
        float* __restrict__ out_idx) {
    const int n  = blockIdx.x * 256 + threadIdx.x;
    const int b  = n >> 12;
    const int hw = n & 4095;
    const float* zp = z + (size_t)b * EMB_DIM * HW + hw;
    REPEAT32(LOADZ)
    Z_SQ_A()
    float best = 3.4e38f;
    int   bidx = 0;
    for (int j = 0; j < NUM_EMB; j += 4) SCAN_GROUP4(j)
    out_idx[n] = (float)bidx;
    const float* eb = emb + (size_t)bidx * EMB_DIM;
    float* op = out_zq + (size_t)b * EMB_DIM * HW + hw;
#pragma unroll
    for (int cc = 0; cc < EMB_DIM; ++cc) op[(size_t)cc * HW] = eb[cc];
}

__global__ __launch_bounds__(256) void vq_combine_kernel(
        const float* __restrict__ emb,
        const unsigned long long* __restrict__ pk,
        float* __restrict__ out_zq, float* __restrict__ out_idx) {
    const int n = blockIdx.x * 256 + threadIdx.x;
    unsigned long long m = pk[n];
#pragma unroll
    for (int y = 1; y < NSPLIT; ++y) {
        unsigned long long v = pk[(size_t)y * N_TOT + n];
        if (v < m) m = v;
    }
    const int bidx = (int)(unsigned)(m & 0xffffffffu);
    out_idx[n] = (float)bidx;
    const int b  = n >> 12;
    const int hw = n & 4095;
    const float* eb = emb + (size_t)bidx * EMB_DIM;
    float* op = out_zq + (size_t)b * EMB_DIM * HW + hw;
#pragma unroll
    for (int cc = 0; cc < EMB_DIM; ++cc) op[(size_t)cc * HW] = eb[cc];
}

extern "C" void kernel_launch(void* const* d_in, const int* in_sizes, int n_in,
                              void* d_out, int out_size, void* d_ws,
                              size_t ws_size, hipStream_t stream) {
    const float* z   = (const float*)d_in[0];
    const float* emb = (const float*)d_in[1];
    char* ws = (char*)d_ws;
    float* out0 = (float*)d_out;
    float* out1 = out0 + (size_t)BATCH * EMB_DIM * HW;

    if (ws_size >= WS_NEED) {
        float*          bq   = (float*)(ws + OFF_BQ);
        unsigned short* eh   = (unsigned short*)(ws + OFF_EH);
        unsigned short* el   = (unsigned short*)(ws + OFF_EL);
        int*            cnt  = (int*)(ws + OFF_CNT);
        int*            cand = (int*)(ws + OFF_CAND);

        hipMemsetAsync(cnt, 0, N_TOT * sizeof(int), stream);
        vq_prep_e<<<NUM_EMB / 256, 256, 0, stream>>>(emb, bq, eh, el);
        vq_filter<<<N_TOT / 256, 256, 0, stream>>>(z, eh, el, bq, cnt, cand);
        vq_pass3<<<N_TOT / 256, 256, 0, stream>>>(z, emb, bq, cnt, cand,
                                                  out0, out1);
    } else if (ws_size >= WS_NEED_R7) {
        float* bq = (float*)ws;
        unsigned long long* pk = (unsigned long long*)(ws + 4096);
        vq_sqnorm_kernel<<<NUM_EMB / 256, 256, 0, stream>>>(emb, bq);
        vq_partial_kernel<<<dim3(N_TOT / 128, NSPLIT), 128, 0, stream>>>(
            z, emb, bq, pk);
        vq_combine_kernel<<<N_TOT / 256, 256, 0, stream>>>(emb, pk, out0, out1);
    } else {
        float* bq = (float*)ws;
        vq_sqnorm_kernel<<<NUM_EMB / 256, 256, 0, stream>>>(emb, bq);
        vq_main_kernel<<<N_TOT / 256, 256, 0, stream>>>(z, emb, bq, out0, out1);
    }
}

// Round 11
// 343.189 us; speedup vs baseline: 1.3863x; 1.3863x over previous
//
#include <hip/hip_runtime.h>

// VectorQuantizer: z[32,32,64,64] f32 (BCHW), emb[1024,32] f32.
// out = concat( z_q[32,32,64,64] f32 , idx[131072] stored as f32 values ).
//
// R11: fused MFMA filter (chunked LDS codebook) + exact rescore.
//  - R10 staging bug fixed: full 32-short rows staged (8 uint2/thread/array).
//  - Per-lane (m1,i1,m2,i2,m3) tracking: flag i1,i2 if within margin of the
//    global min; full-rescan a query only if the lane's 3rd-best is also
//    within margin (needs >=3 in-margin codes on one lane, ~1e-4 of queries)
//    -> pass3 almost never full-scans (R10's 360us pathology gone).
//  - pass3 rescores candidates with the verified numpy-fp32-exact chain
//    (a = pairwise32(z*z), m = ascending-k fmaf, d = fl(fl(a+bq)-fl(2m)));
//    u64 (d,idx) key min == np.argmin first-occurrence tie-break.

#define NUM_EMB 1024
#define EMB_DIM 32
#define HW      4096
#define BATCH   32
#define N_TOT   (BATCH * HW)  // 131072
#define NSPLIT  4
#define CODES_PER (NUM_EMB / NSPLIT)
#define MARGIN  1.0e-4f
#define CHUNK   256
#define ESTRIDE 36            // LDS row stride in shorts (bank-conflict pad)

// ws layout
#define OFF_BQ   0u
#define OFF_EH   4096u
#define OFF_EL   69632u
#define OFF_CNT  135168u
#define OFF_CAND 659456u
#define WS_NEED  4853760u
#define WS_NEED_R7 (4096u + 4u * 131072u * 8u)

using bf16x8 = __attribute__((ext_vector_type(8))) short;
using bf16x4 = __attribute__((ext_vector_type(4))) short;
using f32x4  = __attribute__((ext_vector_type(4))) float;

#define REPEAT32(M) \
    M(0)  M(1)  M(2)  M(3)  M(4)  M(5)  M(6)  M(7)  \
    M(8)  M(9)  M(10) M(11) M(12) M(13) M(14) M(15) \
    M(16) M(17) M(18) M(19) M(20) M(21) M(22) M(23) \
    M(24) M(25) M(26) M(27) M(28) M(29) M(30) M(31)

__device__ __forceinline__ unsigned short bf16_rne(float x) {
    unsigned u = __float_as_uint(x);
    return (unsigned short)((u + 0x7FFFu + ((u >> 16) & 1u)) >> 16);
}

__device__ __forceinline__ float pairwise_sq32(const float* __restrict__ e) {
    float r0 = __fmul_rn(e[0], e[0]), r1 = __fmul_rn(e[1], e[1]);
    float r2 = __fmul_rn(e[2], e[2]), r3 = __fmul_rn(e[3], e[3]);
    float r4 = __fmul_rn(e[4], e[4]), r5 = __fmul_rn(e[5], e[5]);
    float r6 = __fmul_rn(e[6], e[6]), r7 = __fmul_rn(e[7], e[7]);
#pragma unroll
    for (int i = 8; i < 32; i += 8) {
        r0 = __fadd_rn(r0, __fmul_rn(e[i + 0], e[i + 0]));
        r1 = __fadd_rn(r1, __fmul_rn(e[i + 1], e[i + 1]));
        r2 = __fadd_rn(r2, __fmul_rn(e[i + 2], e[i + 2]));
        r3 = __fadd_rn(r3, __fmul_rn(e[i + 3], e[i + 3]));
        r4 = __fadd_rn(r4, __fmul_rn(e[i + 4], e[i + 4]));
        r5 = __fadd_rn(r5, __fmul_rn(e[i + 5], e[i + 5]));
        r6 = __fadd_rn(r6, __fmul_rn(e[i + 6], e[i + 6]));
        r7 = __fadd_rn(r7, __fmul_rn(e[i + 7], e[i + 7]));
    }
    return __fadd_rn(__fadd_rn(__fadd_rn(r0, r1), __fadd_rn(r2, r3)),
                     __fadd_rn(__fadd_rn(r4, r5), __fadd_rn(r6, r7)));
}

__device__ __forceinline__ void store_row16(unsigned short* dst,
                                            const unsigned short* v) {
    unsigned w[16];
#pragma unroll
    for (int i = 0; i < 16; ++i)
        w[i] = (unsigned)v[2 * i] | ((unsigned)v[2 * i + 1] << 16);
    uint4* d4 = (uint4*)dst;
    d4[0] = make_uint4(w[0], w[1], w[2], w[3]);
    d4[1] = make_uint4(w[4], w[5], w[6], w[7]);
    d4[2] = make_uint4(w[8], w[9], w[10], w[11]);
    d4[3] = make_uint4(w[12], w[13], w[14], w[15]);
}

// ---- prep_e: bq exact + eh/el bf16 split ----------------------------------
__global__ __launch_bounds__(256) void vq_prep_e(
        const float* __restrict__ emb, float* __restrict__ bq,
        unsigned short* __restrict__ eh, unsigned short* __restrict__ el) {
    const int j = blockIdx.x * 256 + threadIdx.x;
    if (j >= NUM_EMB) return;
    const float* e = emb + j * EMB_DIM;
    bq[j] = pairwise_sq32(e);
    unsigned short h[32], l[32];
#pragma unroll
    for (int c = 0; c < 32; ++c) {
        float v = e[c];
        unsigned short hb = bf16_rne(v);
        float hf = __uint_as_float((unsigned)hb << 16);
        l[c] = bf16_rne(v - hf);
        h[c] = hb;
    }
    store_row16(eh + (size_t)j * 32, h);
    store_row16(el + (size_t)j * 32, l);
}

__device__ __forceinline__ bf16x8 lds_read8(const short* p) {
    bf16x4 a = *(const bf16x4*)p;        // 8B-aligned ds_read_b64
    bf16x4 b = *(const bf16x4*)(p + 4);
    return __builtin_shufflevector(a, b, 0, 1, 2, 3, 4, 5, 6, 7);
}

// ---- fused filter ---------------------------------------------------------
// Block = 256 thr = 4 waves; wave handles 32 queries (2 MFMA tiles); block
// handles 128 queries. Codebook scanned in 4 chunks of 256 codes in LDS.
// A frag: A[m=cloc][k=quad*8+e] from z (bf16 hi/lo split in-register).
// B frag: B[k][n=cloc] from LDS. D: query row = quad*4+r, code col = cloc.
__global__ __launch_bounds__(256, 4) void vq_filter(
        const float* __restrict__ z,
        const unsigned short* __restrict__ eh,
        const unsigned short* __restrict__ el,
        const float* __restrict__ bq, int* __restrict__ cnt,
        int* __restrict__ cand) {
    __shared__ __align__(16) short seh[CHUNK * ESTRIDE];
    __shared__ __align__(16) short sel[CHUNK * ESTRIDE];
    __shared__ float sbq[CHUNK];

    const int tid  = threadIdx.x;
    const int lane = tid & 63;
    const int wv   = tid >> 6;
    const int cloc = lane & 15, quad = lane >> 4;
    const int qbase = blockIdx.x * 128 + wv * 32;

    // A-fragments straight from z, bf16 hi/lo split
    bf16x8 azh[2], azl[2];
#pragma unroll
    for (int t = 0; t < 2; ++t) {
        const int q  = qbase + t * 16 + cloc;
        const int b  = q >> 12;
        const int hw = q & 4095;
        const float* zb = z + ((size_t)b * EMB_DIM + quad * 8) * HW + hw;
#pragma unroll
        for (int k = 0; k < 8; ++k) {
            float v = zb[(size_t)k * HW];
            unsigned short hb = bf16_rne(v);
            float hf = __uint_as_float((unsigned)hb << 16);
            azh[t][k] = (short)hb;
            azl[t][k] = (short)bf16_rne(v - hf);
        }
    }

    float m1[2][4], m2[2][4], m3[2][4];
    int   i1[2][4], i2[2][4];
#pragma unroll
    for (int t = 0; t < 2; ++t)
#pragma unroll
        for (int r = 0; r < 4; ++r) {
            m1[t][r] = 3.4e38f; m2[t][r] = 3.4e38f; m3[t][r] = 3.4e38f;
            i1[t][r] = 0;       i2[t][r] = 0;
        }

    for (int ch = 0; ch < 4; ++ch) {
        if (ch) __syncthreads();   // all waves done with previous chunk
        // stage 256 full rows (32 shorts each): 2048 uint2 per array
#pragma unroll
        for (int i = 0; i < 8; ++i) {
            const int chunk = i * 256 + tid;      // 0..2047
            const int r = chunk >> 3, c = chunk & 7;   // c: 8 x 4-short pieces
            *(uint2*)&seh[r * ESTRIDE + c * 4] =
                *(const uint2*)(eh + (size_t)(ch * CHUNK + r) * 32 + c * 4);
            *(uint2*)&sel[r * ESTRIDE + c * 4] =
                *(const uint2*)(el + (size_t)(ch * CHUNK + r) * 32 + c * 4);
        }
        sbq[tid] = bq[ch * CHUNK + tid];
        __syncthreads();

        for (int jt = 0; jt < 16; ++jt) {
            const int row = jt * 16 + cloc;
            bf16x8 efh = lds_read8(&seh[row * ESTRIDE + quad * 8]);
            bf16x8 efl = lds_read8(&sel[row * ESTRIDE + quad * 8]);
            const float bqv = sbq[row];
            const int jts = ch * 16 + jt;         // tile index (code = jts*16+cloc)
#pragma unroll
            for (int t = 0; t < 2; ++t) {
                f32x4 acc = {0.f, 0.f, 0.f, 0.f};
                acc = __builtin_amdgcn_mfma_f32_16x16x32_bf16(azl[t], efh, acc, 0, 0, 0);
                acc = __builtin_amdgcn_mfma_f32_16x16x32_bf16(azh[t], efl, acc, 0, 0, 0);
                acc = __builtin_amdgcn_mfma_f32_16x16x32_bf16(azh[t], efh, acc, 0, 0, 0);
#pragma unroll
                for (int r = 0; r < 4; ++r) {
                    const float tt = __fmaf_rn(-2.0f, acc[r], bqv);
                    const bool l1 = tt < m1[t][r];
                    const bool l2 = tt < m2[t][r];
                    const bool l3 = tt < m3[t][r];
                    // order matters: m3 from old m2; m2/i2 from old m1/i1
                    m3[t][r] = l2 ? m2[t][r] : (l3 ? tt : m3[t][r]);
                    m2[t][r] = l1 ? m1[t][r] : (l2 ? tt : m2[t][r]);
                    i2[t][r] = l1 ? i1[t][r] : (l2 ? jts : i2[t][r]);
                    m1[t][r] = l1 ? tt  : m1[t][r];
                    i1[t][r] = l1 ? jts : i1[t][r];
                }
            }
        }
    }

    // global min per query across the 16 cloc lanes
    float g[2][4];
#pragma unroll
    for (int t = 0; t < 2; ++t)
#pragma unroll
        for (int r = 0; r < 4; ++r) g[t][r] = m1[t][r];
#pragma unroll
    for (int off = 1; off < 16; off <<= 1)
#pragma unroll
        for (int t = 0; t < 2; ++t)
#pragma unroll
            for (int r = 0; r < 4; ++r)
                g[t][r] = fminf(g[t][r], __shfl_xor(g[t][r], off, 64));

    // flag up to 2 candidates per lane; 3rd-in-margin on a lane -> rescan
#pragma unroll
    for (int t = 0; t < 2; ++t)
#pragma unroll
        for (int r = 0; r < 4; ++r) {
            const float thr = g[t][r] + MARGIN;
            const int q = qbase + t * 16 + quad * 4 + r;
            if (m1[t][r] <= thr) {
                int pos = atomicAdd(&cnt[q], 1);
                if (pos < 8) cand[(q << 3) + pos] = i1[t][r] * 16 + cloc;
            }
            if (m2[t][r] <= thr) {
                int pos = atomicAdd(&cnt[q], 1);
                if (pos < 8) cand[(q << 3) + pos] = i2[t][r] * 16 + cloc;
            }
            if (m3[t][r] <= thr) atomicAdd(&cnt[q], 1000);
        }
}

// ---- pass3: exact rescore of candidates, write idx + z_q ------------------
#define LOADZ(c) float z##c = zp[(size_t)(c) * HW];
#define Z_SQ_A()                                                              \
    float r0 = __fmul_rn(z0, z0), r1 = __fmul_rn(z1, z1);                     \
    float r2 = __fmul_rn(z2, z2), r3 = __fmul_rn(z3, z3);                     \
    float r4 = __fmul_rn(z4, z4), r5 = __fmul_rn(z5, z5);                     \
    float r6 = __fmul_rn(z6, z6), r7 = __fmul_rn(z7, z7);                     \
    r0 = __fadd_rn(r0, __fmul_rn(z8,  z8));  r0 = __fadd_rn(r0, __fmul_rn(z16, z16)); \
    r0 = __fadd_rn(r0, __fmul_rn(z24, z24));                                  \
    r1 = __fadd_rn(r1, __fmul_rn(z9,  z9));  r1 = __fadd_rn(r1, __fmul_rn(z17, z17)); \
    r1 = __fadd_rn(r1, __fmul_rn(z25, z25));                                  \
    r2 = __fadd_rn(r2, __fmul_rn(z10, z10)); r2 = __fadd_rn(r2, __fmul_rn(z18, z18)); \
    r2 = __fadd_rn(r2, __fmul_rn(z26, z26));                                  \
    r3 = __fadd_rn(r3, __fmul_rn(z11, z11)); r3 = __fadd_rn(r3, __fmul_rn(z19, z19)); \
    r3 = __fadd_rn(r3, __fmul_rn(z27, z27));                                  \
    r4 = __fadd_rn(r4, __fmul_rn(z12, z12)); r4 = __fadd_rn(r4, __fmul_rn(z20, z20)); \
    r4 = __fadd_rn(r4, __fmul_rn(z28, z28));                                  \
    r5 = __fadd_rn(r5, __fmul_rn(z13, z13)); r5 = __fadd_rn(r5, __fmul_rn(z21, z21)); \
    r5 = __fadd_rn(r5, __fmul_rn(z29, z29));                                  \
    r6 = __fadd_rn(r6, __fmul_rn(z14, z14)); r6 = __fadd_rn(r6, __fmul_rn(z22, z22)); \
    r6 = __fadd_rn(r6, __fmul_rn(z30, z30));                                  \
    r7 = __fadd_rn(r7, __fmul_rn(z15, z15)); r7 = __fadd_rn(r7, __fmul_rn(z23, z23)); \
    r7 = __fadd_rn(r7, __fmul_rn(z31, z31));                                  \
    const float a = __fadd_rn(                                                \
        __fadd_rn(__fadd_rn(r0, r1), __fadd_rn(r2, r3)),                      \
        __fadd_rn(__fadd_rn(r4, r5), __fadd_rn(r6, r7)));

#define FMA1(k) m = __fmaf_rn(z##k, e[(k)], m);
#define EXACT_KEY(jv)                                                         \
    {                                                                         \
        const float* e = emb + (size_t)(jv) * EMB_DIM;                        \
        float m = 0.0f;                                                       \
        REPEAT32(FMA1)                                                        \
        float d = __fsub_rn(__fadd_rn(a, bq[(jv)]), __fmul_rn(2.0f, m));      \
        unsigned u = __float_as_uint(d);                                      \
        u = (u & 0x80000000u) ? ~u : (u | 0x80000000u);                       \
        unsigned long long kk =                                               \
            ((unsigned long long)u << 32) | (unsigned)(jv);                   \
        if (kk < bestk) bestk = kk;                                           \
    }

__global__ __launch_bounds__(256, 2) void vq_pass3(
        const float* __restrict__ z, const float* __restrict__ emb,
        const float* __restrict__ bq, const int* __restrict__ cnt,
        const int* __restrict__ cand, float* __restrict__ out_zq,
        float* __restrict__ out_idx) {
    const int n  = blockIdx.x * 256 + threadIdx.x;
    const int b  = n >> 12;
    const int hw = n & 4095;
    const float* zp = z + (size_t)b * EMB_DIM * HW + hw;
    REPEAT32(LOADZ)
    Z_SQ_A()

    const int c = cnt[n];
    unsigned long long bestk = ~0ull;
    if (c >= 1 && c <= 8) {
        for (int i = 0; i < c; ++i) { const int jv = cand[(n << 3) + i]; EXACT_KEY(jv) }
    } else {  // overflow / breakage safety: full exact scan
        for (int jv = 0; jv < NUM_EMB; ++jv) EXACT_KEY(jv)
    }
    const int bidx = (int)(unsigned)(bestk & 0xffffffffu);
    out_idx[n] = (float)bidx;
    const float* eb = emb + (size_t)bidx * EMB_DIM;
    float* op = out_zq + (size_t)b * EMB_DIM * HW + hw;
#pragma unroll
    for (int cc = 0; cc < EMB_DIM; ++cc) op[(size_t)cc * HW] = eb[cc];
}

// ================== proven R7/R5 exhaustive fallback =======================
#define SCAN_GROUP4(j)                                                        \
    {                                                                         \
        const float* e = emb + (size_t)(j) * EMB_DIM;                         \
        const float bq0 = bq[(j) + 0], bq1 = bq[(j) + 1];                     \
        const float bq2 = bq[(j) + 2], bq3 = bq[(j) + 3];                     \
        float m0 = 0.0f, m1 = 0.0f, m2 = 0.0f, m3 = 0.0f;                     \
        REPEAT32(FMA_K)                                                       \
        float d0 = __fsub_rn(__fadd_rn(a, bq0), __fmul_rn(2.0f, m0));         \
        float d1 = __fsub_rn(__fadd_rn(a, bq1), __fmul_rn(2.0f, m1));         \
        float d2 = __fsub_rn(__fadd_rn(a, bq2), __fmul_rn(2.0f, m2));         \
        float d3 = __fsub_rn(__fadd_rn(a, bq3), __fmul_rn(2.0f, m3));         \
        if (d0 < best) { best = d0; bidx = (j) + 0; }                         \
        if (d1 < best) { best = d1; bidx = (j) + 1; }                         \
        if (d2 < best) { best = d2; bidx = (j) + 2; }                         \
        if (d3 < best) { best = d3; bidx = (j) + 3; }                         \
    }
#define FMA_K(k) \
        m0 = __fmaf_rn(z##k, e[0 * EMB_DIM + (k)], m0); \
        m1 = __fmaf_rn(z##k, e[1 * EMB_DIM + (k)], m1); \
        m2 = __fmaf_rn(z##k, e[2 * EMB_DIM + (k)], m2); \
        m3 = __fmaf_rn(z##k, e[3 * EMB_DIM + (k)], m3);

__global__ __launch_bounds__(256) void vq_sqnorm_kernel(
        const float* __restrict__ emb, float* __restrict__ bq) {
    int j = blockIdx.x * 256 + threadIdx.x;
    if (j < NUM_EMB) bq[j] = pairwise_sq32(emb + j * EMB_DIM);
}

__global__ __launch_bounds__(128, 4) void vq_partial_kernel(
        const float* __restrict__ z, const float* __restrict__ emb,
        const float* __restrict__ bq, unsigned long long* __restrict__ pk) {
    const int n  = blockIdx.x * 128 + threadIdx.x;
    const int b  = n >> 12;
    const int hw = n & 4095;
    const float* zp = z + (size_t)b * EMB_DIM * HW + hw;
    REPEAT32(LOADZ)
    Z_SQ_A()
    const int j0 = blockIdx.y * CODES_PER;
    float best = 3.4e38f;
    int   bidx = j0;
    for (int j = j0; j < j0 + CODES_PER; j += 4) SCAN_GROUP4(j)
    pk[(size_t)blockIdx.y * N_TOT + n] =
        ((unsigned long long)__float_as_uint(best) << 32) | (unsigned)bidx;
}

__global__ __launch_bounds__(256, 2) void vq_main_kernel(
        const float* __restrict__ z, const float* __restrict__ emb,
        const float* __restrict__ bq, float* __restrict__ out_zq,
        float* __restrict__ out_idx) {
    const int n  = blockIdx.x * 256 + threadIdx.x;
    const int b  = n >> 12;
    const int hw = n & 4095;
    const float* zp = z + (size_t)b * EMB_DIM * HW + hw;
    REPEAT32(LOADZ)
    Z_SQ_A()
    float best = 3.4e38f;
    int   bidx = 0;
    for (int j = 0; j < NUM_EMB; j += 4) SCAN_GROUP4(j)
    out_idx[n] = (float)bidx;
    const float* eb = emb + (size_t)bidx * EMB_DIM;
    float* op = out_zq + (size_t)b * EMB_DIM * HW + hw;
#pragma unroll
    for (int cc = 0; cc < EMB_DIM; ++cc) op[(size_t)cc * HW] = eb[cc];
}

__global__ __launch_bounds__(256) void vq_combine_kernel(
        const float* __restrict__ emb,
        const unsigned long long* __restrict__ pk,
        float* __restrict__ out_zq, float* __restrict__ out_idx) {
    const int n = blockIdx.x * 256 + threadIdx.x;
    unsigned long long m = pk[n];
#pragma unroll
    for (int y = 1; y < NSPLIT; ++y) {
        unsigned long long v = pk[(size_t)y * N_TOT + n];
        if (v < m) m = v;
    }
    const int bidx = (int)(unsigned)(m & 0xffffffffu);
    out_idx[n] = (float)bidx;
    const int b  = n >> 12;
    const int hw = n & 4095;
    const float* eb = emb + (size_t)bidx * EMB_DIM;
    float* op = out_zq + (size_t)b * EMB_DIM * HW + hw;
#pragma unroll
    for (int cc = 0; cc < EMB_DIM; ++cc) op[(size_t)cc * HW] = eb[cc];
}

extern "C" void kernel_launch(void* const* d_in, const int* in_sizes, int n_in,
                              void* d_out, int out_size, void* d_ws,
                              size_t ws_size, hipStream_t stream) {
    const float* z   = (const float*)d_in[0];
    const float* emb = (const float*)d_in[1];
    char* ws = (char*)d_ws;
    float* out0 = (float*)d_out;
    float* out1 = out0 + (size_t)BATCH * EMB_DIM * HW;

    if (ws_size >= WS_NEED) {
        float*          bq   = (float*)(ws + OFF_BQ);
        unsigned short* eh   = (unsigned short*)(ws + OFF_EH);
        unsigned short* el   = (unsigned short*)(ws + OFF_EL);
        int*            cnt  = (int*)(ws + OFF_CNT);
        int*            cand = (int*)(ws + OFF_CAND);

        hipMemsetAsync(cnt, 0, N_TOT * sizeof(int), stream);
        vq_prep_e<<<NUM_EMB / 256, 256, 0, stream>>>(emb, bq, eh, el);
        vq_filter<<<N_TOT / 128, 256, 0, stream>>>(z, eh, el, bq, cnt, cand);
        vq_pass3<<<N_TOT / 256, 256, 0, stream>>>(z, emb, bq, cnt, cand,
                                                  out0, out1);
    } else if (ws_size >= WS_NEED_R7) {
        float* bq = (float*)ws;
        unsigned long long* pk = (unsigned long long*)(ws + 4096);
        vq_sqnorm_kernel<<<NUM_EMB / 256, 256, 0, stream>>>(emb, bq);
        vq_partial_kernel<<<dim3(N_TOT / 128, NSPLIT), 128, 0, stream>>>(
            z, emb, bq, pk);
        vq_combine_kernel<<<N_TOT / 256, 256, 0, stream>>>(emb, pk, out0, out1);
    } else {
        float* bq = (float*)ws;
        vq_sqnorm_kernel<<<NUM_EMB / 256, 256, 0, stream>>>(emb, bq);
        vq_main_kernel<<<N_TOT / 256, 256, 0, stream>>>(z, emb, bq, out0, out1);
    }
}

// Round 12
// 150.182 us; speedup vs baseline: 3.1678x; 2.2852x over previous
//
#include <hip/hip_runtime.h>

// VectorQuantizer: z[32,32,64,64] f32 (BCHW), emb[1024,32] f32.
// out = concat( z_q[32,32,64,64] f32 , idx[131072] stored as f32 values ).
//
// R12: R11's straggler fix. pass3's overflow path (cnt==0 or >8, i.e. the
// filter couldn't bound the argmin to <=8 candidates) no longer runs a
// serial in-thread 1024-code scan (R11: one latency-bound wave = 226 us);
// it appends the query to an overflow list, and vq_fixup processes the list
// block-per-query (256 thr x 4 codes, exact numpy-fp32 chain, u64 (d,idx)
// key LDS-min -> first-index tie-break). Filter & margins unchanged.

#define NUM_EMB 1024
#define EMB_DIM 32
#define HW      4096
#define BATCH   32
#define N_TOT   (BATCH * HW)  // 131072
#define NSPLIT  4
#define CODES_PER (NUM_EMB / NSPLIT)
#define MARGIN  1.0e-4f
#define CHUNK   256
#define ESTRIDE 36            // LDS row stride in shorts (bank-conflict pad)
#define OVF_CAP 131072

// ws layout
#define OFF_BQ   0u
#define OFF_EH   4096u
#define OFF_EL   69632u
#define OFF_CNT  135168u
#define OFF_CAND 659456u
#define OFF_OVFC 4853760u
#define OFF_OVFL 4853776u
#define WS_NEED  5378064u
#define WS_NEED_R7 (4096u + 4u * 131072u * 8u)

using bf16x8 = __attribute__((ext_vector_type(8))) short;
using bf16x4 = __attribute__((ext_vector_type(4))) short;
using f32x4  = __attribute__((ext_vector_type(4))) float;

#define REPEAT32(M) \
    M(0)  M(1)  M(2)  M(3)  M(4)  M(5)  M(6)  M(7)  \
    M(8)  M(9)  M(10) M(11) M(12) M(13) M(14) M(15) \
    M(16) M(17) M(18) M(19) M(20) M(21) M(22) M(23) \
    M(24) M(25) M(26) M(27) M(28) M(29) M(30) M(31)

__device__ __forceinline__ unsigned short bf16_rne(float x) {
    unsigned u = __float_as_uint(x);
    return (unsigned short)((u + 0x7FFFu + ((u >> 16) & 1u)) >> 16);
}

__device__ __forceinline__ float pairwise_sq32(const float* __restrict__ e) {
    float r0 = __fmul_rn(e[0], e[0]), r1 = __fmul_rn(e[1], e[1]);
    float r2 = __fmul_rn(e[2], e[2]), r3 = __fmul_rn(e[3], e[3]);
    float r4 = __fmul_rn(e[4], e[4]), r5 = __fmul_rn(e[5], e[5]);
    float r6 = __fmul_rn(e[6], e[6]), r7 = __fmul_rn(e[7], e[7]);
#pragma unroll
    for (int i = 8; i < 32; i += 8) {
        r0 = __fadd_rn(r0, __fmul_rn(e[i + 0], e[i + 0]));
        r1 = __fadd_rn(r1, __fmul_rn(e[i + 1], e[i + 1]));
        r2 = __fadd_rn(r2, __fmul_rn(e[i + 2], e[i + 2]));
        r3 = __fadd_rn(r3, __fmul_rn(e[i + 3], e[i + 3]));
        r4 = __fadd_rn(r4, __fmul_rn(e[i + 4], e[i + 4]));
        r5 = __fadd_rn(r5, __fmul_rn(e[i + 5], e[i + 5]));
        r6 = __fadd_rn(r6, __fmul_rn(e[i + 6], e[i + 6]));
        r7 = __fadd_rn(r7, __fmul_rn(e[i + 7], e[i + 7]));
    }
    return __fadd_rn(__fadd_rn(__fadd_rn(r0, r1), __fadd_rn(r2, r3)),
                     __fadd_rn(__fadd_rn(r4, r5), __fadd_rn(r6, r7)));
}

__device__ __forceinline__ void store_row16(unsigned short* dst,
                                            const unsigned short* v) {
    unsigned w[16];
#pragma unroll
    for (int i = 0; i < 16; ++i)
        w[i] = (unsigned)v[2 * i] | ((unsigned)v[2 * i + 1] << 16);
    uint4* d4 = (uint4*)dst;
    d4[0] = make_uint4(w[0], w[1], w[2], w[3]);
    d4[1] = make_uint4(w[4], w[5], w[6], w[7]);
    d4[2] = make_uint4(w[8], w[9], w[10], w[11]);
    d4[3] = make_uint4(w[12], w[13], w[14], w[15]);
}

// ---- prep_e: bq exact + eh/el bf16 split + zero overflow counter ----------
__global__ __launch_bounds__(256) void vq_prep_e(
        const float* __restrict__ emb, float* __restrict__ bq,
        unsigned short* __restrict__ eh, unsigned short* __restrict__ el,
        int* __restrict__ ovfc) {
    const int j = blockIdx.x * 256 + threadIdx.x;
    if (j == 0) *ovfc = 0;
    if (j >= NUM_EMB) return;
    const float* e = emb + j * EMB_DIM;
    bq[j] = pairwise_sq32(e);
    unsigned short h[32], l[32];
#pragma unroll
    for (int c = 0; c < 32; ++c) {
        float v = e[c];
        unsigned short hb = bf16_rne(v);
        float hf = __uint_as_float((unsigned)hb << 16);
        l[c] = bf16_rne(v - hf);
        h[c] = hb;
    }
    store_row16(eh + (size_t)j * 32, h);
    store_row16(el + (size_t)j * 32, l);
}

__device__ __forceinline__ bf16x8 lds_read8(const short* p) {
    bf16x4 a = *(const bf16x4*)p;        // 8B-aligned ds_read_b64
    bf16x4 b = *(const bf16x4*)(p + 4);
    return __builtin_shufflevector(a, b, 0, 1, 2, 3, 4, 5, 6, 7);
}

// ---- fused filter (unchanged from R11) ------------------------------------
__global__ __launch_bounds__(256, 4) void vq_filter(
        const float* __restrict__ z,
        const unsigned short* __restrict__ eh,
        const unsigned short* __restrict__ el,
        const float* __restrict__ bq, int* __restrict__ cnt,
        int* __restrict__ cand) {
    __shared__ __align__(16) short seh[CHUNK * ESTRIDE];
    __shared__ __align__(16) short sel[CHUNK * ESTRIDE];
    __shared__ float sbq[CHUNK];

    const int tid  = threadIdx.x;
    const int lane = tid & 63;
    const int wv   = tid >> 6;
    const int cloc = lane & 15, quad = lane >> 4;
    const int qbase = blockIdx.x * 128 + wv * 32;

    bf16x8 azh[2], azl[2];
#pragma unroll
    for (int t = 0; t < 2; ++t) {
        const int q  = qbase + t * 16 + cloc;
        const int b  = q >> 12;
        const int hw = q & 4095;
        const float* zb = z + ((size_t)b * EMB_DIM + quad * 8) * HW + hw;
#pragma unroll
        for (int k = 0; k < 8; ++k) {
            float v = zb[(size_t)k * HW];
            unsigned short hb = bf16_rne(v);
            float hf = __uint_as_float((unsigned)hb << 16);
            azh[t][k] = (short)hb;
            azl[t][k] = (short)bf16_rne(v - hf);
        }
    }

    float m1[2][4], m2[2][4], m3[2][4];
    int   i1[2][4], i2[2][4];
#pragma unroll
    for (int t = 0; t < 2; ++t)
#pragma unroll
        for (int r = 0; r < 4; ++r) {
            m1[t][r] = 3.4e38f; m2[t][r] = 3.4e38f; m3[t][r] = 3.4e38f;
            i1[t][r] = 0;       i2[t][r] = 0;
        }

    for (int ch = 0; ch < 4; ++ch) {
        if (ch) __syncthreads();
#pragma unroll
        for (int i = 0; i < 8; ++i) {
            const int chunk = i * 256 + tid;           // 0..2047
            const int r = chunk >> 3, c = chunk & 7;   // 8 x 4-short pieces
            *(uint2*)&seh[r * ESTRIDE + c * 4] =
                *(const uint2*)(eh + (size_t)(ch * CHUNK + r) * 32 + c * 4);
            *(uint2*)&sel[r * ESTRIDE + c * 4] =
                *(const uint2*)(el + (size_t)(ch * CHUNK + r) * 32 + c * 4);
        }
        sbq[tid] = bq[ch * CHUNK + tid];
        __syncthreads();

        for (int jt = 0; jt < 16; ++jt) {
            const int row = jt * 16 + cloc;
            bf16x8 efh = lds_read8(&seh[row * ESTRIDE + quad * 8]);
            bf16x8 efl = lds_read8(&sel[row * ESTRIDE + quad * 8]);
            const float bqv = sbq[row];
            const int jts = ch * 16 + jt;
#pragma unroll
            for (int t = 0; t < 2; ++t) {
                f32x4 acc = {0.f, 0.f, 0.f, 0.f};
                acc = __builtin_amdgcn_mfma_f32_16x16x32_bf16(azl[t], efh, acc, 0, 0, 0);
                acc = __builtin_amdgcn_mfma_f32_16x16x32_bf16(azh[t], efl, acc, 0, 0, 0);
                acc = __builtin_amdgcn_mfma_f32_16x16x32_bf16(azh[t], efh, acc, 0, 0, 0);
#pragma unroll
                for (int r = 0; r < 4; ++r) {
                    const float tt = __fmaf_rn(-2.0f, acc[r], bqv);
                    const bool l1 = tt < m1[t][r];
                    const bool l2 = tt < m2[t][r];
                    const bool l3 = tt < m3[t][r];
                    m3[t][r] = l2 ? m2[t][r] : (l3 ? tt : m3[t][r]);
                    m2[t][r] = l1 ? m1[t][r] : (l2 ? tt : m2[t][r]);
                    i2[t][r] = l1 ? i1[t][r] : (l2 ? jts : i2[t][r]);
                    m1[t][r] = l1 ? tt  : m1[t][r];
                    i1[t][r] = l1 ? jts : i1[t][r];
                }
            }
        }
    }

    float g[2][4];
#pragma unroll
    for (int t = 0; t < 2; ++t)
#pragma unroll
        for (int r = 0; r < 4; ++r) g[t][r] = m1[t][r];
#pragma unroll
    for (int off = 1; off < 16; off <<= 1)
#pragma unroll
        for (int t = 0; t < 2; ++t)
#pragma unroll
            for (int r = 0; r < 4; ++r)
                g[t][r] = fminf(g[t][r], __shfl_xor(g[t][r], off, 64));

#pragma unroll
    for (int t = 0; t < 2; ++t)
#pragma unroll
        for (int r = 0; r < 4; ++r) {
            const float thr = g[t][r] + MARGIN;
            const int q = qbase + t * 16 + quad * 4 + r;
            if (m1[t][r] <= thr) {
                int pos = atomicAdd(&cnt[q], 1);
                if (pos < 8) cand[(q << 3) + pos] = i1[t][r] * 16 + cloc;
            }
            if (m2[t][r] <= thr) {
                int pos = atomicAdd(&cnt[q], 1);
                if (pos < 8) cand[(q << 3) + pos] = i2[t][r] * 16 + cloc;
            }
            if (m3[t][r] <= thr) atomicAdd(&cnt[q], 1000);
        }
}

// ---- exact-rescore building blocks (verified numpy-fp32 chain) ------------
#define LOADZ(c) float z##c = zp[(size_t)(c) * HW];
#define Z_SQ_A()                                                              \
    float r0 = __fmul_rn(z0, z0), r1 = __fmul_rn(z1, z1);                     \
    float r2 = __fmul_rn(z2, z2), r3 = __fmul_rn(z3, z3);                     \
    float r4 = __fmul_rn(z4, z4), r5 = __fmul_rn(z5, z5);                     \
    float r6 = __fmul_rn(z6, z6), r7 = __fmul_rn(z7, z7);                     \
    r0 = __fadd_rn(r0, __fmul_rn(z8,  z8));  r0 = __fadd_rn(r0, __fmul_rn(z16, z16)); \
    r0 = __fadd_rn(r0, __fmul_rn(z24, z24));                                  \
    r1 = __fadd_rn(r1, __fmul_rn(z9,  z9));  r1 = __fadd_rn(r1, __fmul_rn(z17, z17)); \
    r1 = __fadd_rn(r1, __fmul_rn(z25, z25));                                  \
    r2 = __fadd_rn(r2, __fmul_rn(z10, z10)); r2 = __fadd_rn(r2, __fmul_rn(z18, z18)); \
    r2 = __fadd_rn(r2, __fmul_rn(z26, z26));                                  \
    r3 = __fadd_rn(r3, __fmul_rn(z11, z11)); r3 = __fadd_rn(r3, __fmul_rn(z19, z19)); \
    r3 = __fadd_rn(r3, __fmul_rn(z27, z27));                                  \
    r4 = __fadd_rn(r4, __fmul_rn(z12, z12)); r4 = __fadd_rn(r4, __fmul_rn(z20, z20)); \
    r4 = __fadd_rn(r4, __fmul_rn(z28, z28));                                  \
    r5 = __fadd_rn(r5, __fmul_rn(z13, z13)); r5 = __fadd_rn(r5, __fmul_rn(z21, z21)); \
    r5 = __fadd_rn(r5, __fmul_rn(z29, z29));                                  \
    r6 = __fadd_rn(r6, __fmul_rn(z14, z14)); r6 = __fadd_rn(r6, __fmul_rn(z22, z22)); \
    r6 = __fadd_rn(r6, __fmul_rn(z30, z30));                                  \
    r7 = __fadd_rn(r7, __fmul_rn(z15, z15)); r7 = __fadd_rn(r7, __fmul_rn(z23, z23)); \
    r7 = __fadd_rn(r7, __fmul_rn(z31, z31));                                  \
    const float a = __fadd_rn(                                                \
        __fadd_rn(__fadd_rn(r0, r1), __fadd_rn(r2, r3)),                      \
        __fadd_rn(__fadd_rn(r4, r5), __fadd_rn(r6, r7)));

#define FMA1(k) m = __fmaf_rn(z##k, e[(k)], m);
#define EXACT_KEY(jv)                                                         \
    {                                                                         \
        const float* e = emb + (size_t)(jv) * EMB_DIM;                        \
        float m = 0.0f;                                                       \
        REPEAT32(FMA1)                                                        \
        float d = __fsub_rn(__fadd_rn(a, bq[(jv)]), __fmul_rn(2.0f, m));      \
        unsigned u = __float_as_uint(d);                                      \
        u = (u & 0x80000000u) ? ~u : (u | 0x80000000u);                       \
        unsigned long long kk =                                               \
            ((unsigned long long)u << 32) | (unsigned)(jv);                   \
        if (kk < bestk) bestk = kk;                                           \
    }

// ---- pass3: rescore candidates; overflow -> list --------------------------
__global__ __launch_bounds__(256, 2) void vq_pass3(
        const float* __restrict__ z, const float* __restrict__ emb,
        const float* __restrict__ bq, const int* __restrict__ cnt,
        const int* __restrict__ cand, int* __restrict__ ovfc,
        int* __restrict__ ovfl, float* __restrict__ out_zq,
        float* __restrict__ out_idx) {
    const int n  = blockIdx.x * 256 + threadIdx.x;
    const int b  = n >> 12;
    const int hw = n & 4095;
    const int c = cnt[n];
    if (c < 1 || c > 8) {                 // filter couldn't bound it
        int pos = atomicAdd(ovfc, 1);
        if (pos < OVF_CAP) { ovfl[pos] = n; return; }
        // cap overflow (unreachable in practice): fall through to full scan
    }
    const float* zp = z + (size_t)b * EMB_DIM * HW + hw;
    REPEAT32(LOADZ)
    Z_SQ_A()

    unsigned long long bestk = ~0ull;
    if (c >= 1 && c <= 8) {
        for (int i = 0; i < c; ++i) { const int jv = cand[(n << 3) + i]; EXACT_KEY(jv) }
    } else {
        for (int jv = 0; jv < NUM_EMB; ++jv) EXACT_KEY(jv)
    }
    const int bidx = (int)(unsigned)(bestk & 0xffffffffu);
    out_idx[n] = (float)bidx;
    const float* eb = emb + (size_t)bidx * EMB_DIM;
    float* op = out_zq + (size_t)b * EMB_DIM * HW + hw;
#pragma unroll
    for (int cc = 0; cc < EMB_DIM; ++cc) op[(size_t)cc * HW] = eb[cc];
}

// ---- fixup: block-per-query exact full scan (parallel over codes) ---------
__global__ __launch_bounds__(256) void vq_fixup(
        const float* __restrict__ z, const float* __restrict__ emb,
        const float* __restrict__ bq, const int* __restrict__ ovfc,
        const int* __restrict__ ovfl, float* __restrict__ out_zq,
        float* __restrict__ out_idx) {
    __shared__ unsigned long long bs[256];
    const int tid = threadIdx.x;
    int total = *ovfc;
    if (total > OVF_CAP) total = OVF_CAP;

    for (int it = blockIdx.x; it < total; it += gridDim.x) {
        const int n  = ovfl[it];
        const int b  = n >> 12;
        const int hw = n & 4095;
        const float* zp = z + (size_t)b * EMB_DIM * HW + hw;  // broadcast loads
        REPEAT32(LOADZ)
        Z_SQ_A()
        unsigned long long bestk = ~0ull;
#pragma unroll
        for (int k = 0; k < 4; ++k) { const int jv = tid * 4 + k; EXACT_KEY(jv) }
        bs[tid] = bestk;
        __syncthreads();
        for (int off = 128; off > 0; off >>= 1) {
            if (tid < off && bs[tid + off] < bs[tid]) bs[tid] = bs[tid + off];
            __syncthreads();
        }
        const int bidx = (int)(unsigned)(bs[0] & 0xffffffffu);
        if (tid == 0) out_idx[n] = (float)bidx;
        if (tid < EMB_DIM)
            out_zq[(size_t)b * EMB_DIM * HW + (size_t)tid * HW + hw] =
                emb[(size_t)bidx * EMB_DIM + tid];
        __syncthreads();
    }
}

// ================== proven R7/R5 exhaustive fallback =======================
#define SCAN_GROUP4(j)                                                        \
    {                                                                         \
        const float* e = emb + (size_t)(j) * EMB_DIM;                         \
        const float bq0 = bq[(j) + 0], bq1 = bq[(j) + 1];                     \
        const float bq2 = bq[(j) + 2], bq3 = bq[(j) + 3];                     \
        float m0 = 0.0f, m1 = 0.0f, m2 = 0.0f, m3 = 0.0f;                     \
        REPEAT32(FMA_K)                                                       \
        float d0 = __fsub_rn(__fadd_rn(a, bq0), __fmul_rn(2.0f, m0));         \
        float d1 = __fsub_rn(__fadd_rn(a, bq1), __fmul_rn(2.0f, m1));         \
        float d2 = __fsub_rn(__fadd_rn(a, bq2), __fmul_rn(2.0f, m2));         \
        float d3 = __fsub_rn(__fadd_rn(a, bq3), __fmul_rn(2.0f, m3));         \
        if (d0 < best) { best = d0; bidx = (j) + 0; }                         \
        if (d1 < best) { best = d1; bidx = (j) + 1; }                         \
        if (d2 < best) { best = d2; bidx = (j) + 2; }                         \
        if (d3 < best) { best = d3; bidx = (j) + 3; }                         \
    }
#define FMA_K(k) \
        m0 = __fmaf_rn(z##k, e[0 * EMB_DIM + (k)], m0); \
        m1 = __fmaf_rn(z##k, e[1 * EMB_DIM + (k)], m1); \
        m2 = __fmaf_rn(z##k, e[2 * EMB_DIM + (k)], m2); \
        m3 = __fmaf_rn(z##k, e[3 * EMB_DIM + (k)], m3);

__global__ __launch_bounds__(256) void vq_sqnorm_kernel(
        const float* __restrict__ emb, float* __restrict__ bq) {
    int j = blockIdx.x * 256 + threadIdx.x;
    if (j < NUM_EMB) bq[j] = pairwise_sq32(emb + j * EMB_DIM);
}

__global__ __launch_bounds__(128, 4) void vq_partial_kernel(
        const float* __restrict__ z, const float* __restrict__ emb,
        const float* __restrict__ bq, unsigned long long* __restrict__ pk) {
    const int n  = blockIdx.x * 128 + threadIdx.x;
    const int b  = n >> 12;
    const int hw = n & 4095;
    const float* zp = z + (size_t)b * EMB_DIM * HW + hw;
    REPEAT32(LOADZ)
    Z_SQ_A()
    const int j0 = blockIdx.y * CODES_PER;
    float best = 3.4e38f;
    int   bidx = j0;
    for (int j = j0; j < j0 + CODES_PER; j += 4) SCAN_GROUP4(j)
    pk[(size_t)blockIdx.y * N_TOT + n] =
        ((unsigned long long)__float_as_uint(best) << 32) | (unsigned)bidx;
}

__global__ __launch_bounds__(256, 2) void vq_main_kernel(
        const float* __restrict__ z, const float* __restrict__ emb,
        const float* __restrict__ bq, float* __restrict__ out_zq,
        float* __restrict__ out_idx) {
    const int n  = blockIdx.x * 256 + threadIdx.x;
    const int b  = n >> 12;
    const int hw = n & 4095;
    const float* zp = z + (size_t)b * EMB_DIM * HW + hw;
    REPEAT32(LOADZ)
    Z_SQ_A()
    float best = 3.4e38f;
    int   bidx = 0;
    for (int j = 0; j < NUM_EMB; j += 4) SCAN_GROUP4(j)
    out_idx[n] = (float)bidx;
    const float* eb = emb + (size_t)bidx * EMB_DIM;
    float* op = out_zq + (size_t)b * EMB_DIM * HW + hw;
#pragma unroll
    for (int cc = 0; cc < EMB_DIM; ++cc) op[(size_t)cc * HW] = eb[cc];
}

__global__ __launch_bounds__(256) void vq_combine_kernel(
        const float* __restrict__ emb,
        const unsigned long long* __restrict__ pk,
        float* __restrict__ out_zq, float* __restrict__ out_idx) {
    const int n = blockIdx.x * 256 + threadIdx.x;
    unsigned long long m = pk[n];
#pragma unroll
    for (int y = 1; y < NSPLIT; ++y) {
        unsigned long long v = pk[(size_t)y * N_TOT + n];
        if (v < m) m = v;
    }
    const int bidx = (int)(unsigned)(m & 0xffffffffu);
    out_idx[n] = (float)bidx;
    const int b  = n >> 12;
    const int hw = n & 4095;
    const float* eb = emb + (size_t)bidx * EMB_DIM;
    float* op = out_zq + (size_t)b * EMB_DIM * HW + hw;
#pragma unroll
    for (int cc = 0; cc < EMB_DIM; ++cc) op[(size_t)cc * HW] = eb[cc];
}

extern "C" void kernel_launch(void* const* d_in, const int* in_sizes, int n_in,
                              void* d_out, int out_size, void* d_ws,
                              size_t ws_size, hipStream_t stream) {
    const float* z   = (const float*)d_in[0];
    const float* emb = (const float*)d_in[1];
    char* ws = (char*)d_ws;
    float* out0 = (float*)d_out;
    float* out1 = out0 + (size_t)BATCH * EMB_DIM * HW;

    if (ws_size >= WS_NEED) {
        float*          bq   = (float*)(ws + OFF_BQ);
        unsigned short* eh   = (unsigned short*)(ws + OFF_EH);
        unsigned short* el   = (unsigned short*)(ws + OFF_EL);
        int*            cnt  = (int*)(ws + OFF_CNT);
        int*            cand = (int*)(ws + OFF_CAND);
        int*            ovfc = (int*)(ws + OFF_OVFC);
        int*            ovfl = (int*)(ws + OFF_OVFL);

        hipMemsetAsync(cnt, 0, N_TOT * sizeof(int), stream);
        vq_prep_e<<<NUM_EMB / 256, 256, 0, stream>>>(emb, bq, eh, el, ovfc);
        vq_filter<<<N_TOT / 128, 256, 0, stream>>>(z, eh, el, bq, cnt, cand);
        vq_pass3<<<N_TOT / 256, 256, 0, stream>>>(z, emb, bq, cnt, cand,
                                                  ovfc, ovfl, out0, out1);
        vq_fixup<<<1024, 256, 0, stream>>>(z, emb, bq, ovfc, ovfl,
                                           out0, out1);
    } else if (ws_size >= WS_NEED_R7) {
        float* bq = (float*)ws;
        unsigned long long* pk = (unsigned long long*)(ws + 4096);
        vq_sqnorm_kernel<<<NUM_EMB / 256, 256, 0, stream>>>(emb, bq);
        vq_partial_kernel<<<dim3(N_TOT / 128, NSPLIT), 128, 0, stream>>>(
            z, emb, bq, pk);
        vq_combine_kernel<<<N_TOT / 256, 256, 0, stream>>>(emb, pk, out0, out1);
    } else {
        float* bq = (float*)ws;
        vq_sqnorm_kernel<<<NUM_EMB / 256, 256, 0, stream>>>(emb, bq);
        vq_main_kernel<<<N_TOT / 256, 256, 0, stream>>>(z, emb, bq, out0, out1);
    }
}

// Round 13
// 140.469 us; speedup vs baseline: 3.3869x; 1.0691x over previous
//
#include <hip/hip_runtime.h>

// VectorQuantizer: z[32,32,64,64] f32 (BCHW), emb[1024,32] f32.
// out = concat( z_q[32,32,64,64] f32 , idx[131072] stored as f32 values ).
//
// R13: filter-epilogue VALU cut. prep_e pre-scales the codebook by -2
// (exact in bf16) and the filter inits the MFMA accumulator with bq, so
// tt = acc[r] with no epilogue fma. Min-tracking reduced to (m1,i1,m2):
// in-margin m1 -> candidate; in-margin m2 -> overflow (parallel exact
// fixup). pass3: cnt==1 means the single candidate IS the argmin (margin
// safety proof) -> no exact math for ~70% of queries. cnt in [2,8] ->
// numpy-bit-exact rescore; else overflow list -> block-per-query fixup.

#define NUM_EMB 1024
#define EMB_DIM 32
#define HW      4096
#define BATCH   32
#define N_TOT   (BATCH * HW)  // 131072
#define NSPLIT  4
#define CODES_PER (NUM_EMB / NSPLIT)
#define MARGIN  1.0e-4f
#define CHUNK   256
#define ESTRIDE 36            // LDS row stride in shorts (bank-conflict pad)
#define OVF_CAP 131072

// ws layout
#define OFF_BQ   0u
#define OFF_EH   4096u
#define OFF_EL   69632u
#define OFF_CNT  135168u
#define OFF_CAND 659456u
#define OFF_OVFC 4853760u
#define OFF_OVFL 4853776u
#define WS_NEED  5378064u
#define WS_NEED_R7 (4096u + 4u * 131072u * 8u)

using bf16x8 = __attribute__((ext_vector_type(8))) short;
using bf16x4 = __attribute__((ext_vector_type(4))) short;
using f32x4  = __attribute__((ext_vector_type(4))) float;

#define REPEAT32(M) \
    M(0)  M(1)  M(2)  M(3)  M(4)  M(5)  M(6)  M(7)  \
    M(8)  M(9)  M(10) M(11) M(12) M(13) M(14) M(15) \
    M(16) M(17) M(18) M(19) M(20) M(21) M(22) M(23) \
    M(24) M(25) M(26) M(27) M(28) M(29) M(30) M(31)

__device__ __forceinline__ unsigned short bf16_rne(float x) {
    unsigned u = __float_as_uint(x);
    return (unsigned short)((u + 0x7FFFu + ((u >> 16) & 1u)) >> 16);
}

__device__ __forceinline__ float pairwise_sq32(const float* __restrict__ e) {
    float r0 = __fmul_rn(e[0], e[0]), r1 = __fmul_rn(e[1], e[1]);
    float r2 = __fmul_rn(e[2], e[2]), r3 = __fmul_rn(e[3], e[3]);
    float r4 = __fmul_rn(e[4], e[4]), r5 = __fmul_rn(e[5], e[5]);
    float r6 = __fmul_rn(e[6], e[6]), r7 = __fmul_rn(e[7], e[7]);
#pragma unroll
    for (int i = 8; i < 32; i += 8) {
        r0 = __fadd_rn(r0, __fmul_rn(e[i + 0], e[i + 0]));
        r1 = __fadd_rn(r1, __fmul_rn(e[i + 1], e[i + 1]));
        r2 = __fadd_rn(r2, __fmul_rn(e[i + 2], e[i + 2]));
        r3 = __fadd_rn(r3, __fmul_rn(e[i + 3], e[i + 3]));
        r4 = __fadd_rn(r4, __fmul_rn(e[i + 4], e[i + 4]));
        r5 = __fadd_rn(r5, __fmul_rn(e[i + 5], e[i + 5]));
        r6 = __fadd_rn(r6, __fmul_rn(e[i + 6], e[i + 6]));
        r7 = __fadd_rn(r7, __fmul_rn(e[i + 7], e[i + 7]));
    }
    return __fadd_rn(__fadd_rn(__fadd_rn(r0, r1), __fadd_rn(r2, r3)),
                     __fadd_rn(__fadd_rn(r4, r5), __fadd_rn(r6, r7)));
}

__device__ __forceinline__ void store_row16(unsigned short* dst,
                                            const unsigned short* v) {
    unsigned w[16];
#pragma unroll
    for (int i = 0; i < 16; ++i)
        w[i] = (unsigned)v[2 * i] | ((unsigned)v[2 * i + 1] << 16);
    uint4* d4 = (uint4*)dst;
    d4[0] = make_uint4(w[0], w[1], w[2], w[3]);
    d4[1] = make_uint4(w[4], w[5], w[6], w[7]);
    d4[2] = make_uint4(w[8], w[9], w[10], w[11]);
    d4[3] = make_uint4(w[12], w[13], w[14], w[15]);
}

// ---- prep_e: bq exact + (-2e) bf16 split + zero cnt/ovfc ------------------
// grid = N_TOT/256 blocks so every cnt[] entry is zeroed inline (no memset).
__global__ __launch_bounds__(256) void vq_prep_e(
        const float* __restrict__ emb, float* __restrict__ bq,
        unsigned short* __restrict__ eh, unsigned short* __restrict__ el,
        int* __restrict__ cnt, int* __restrict__ ovfc) {
    const int g = blockIdx.x * 256 + threadIdx.x;
    cnt[g] = 0;
    if (g == 0) *ovfc = 0;
    if (g >= NUM_EMB) return;
    const float* e = emb + g * EMB_DIM;
    bq[g] = pairwise_sq32(e);
    unsigned short h[32], l[32];
#pragma unroll
    for (int c = 0; c < 32; ++c) {
        float v = -2.0f * e[c];            // exact (power-of-2 scale)
        unsigned short hb = bf16_rne(v);
        float hf = __uint_as_float((unsigned)hb << 16);
        l[c] = bf16_rne(v - hf);
        h[c] = hb;
    }
    store_row16(eh + (size_t)g * 32, h);
    store_row16(el + (size_t)g * 32, l);
}

__device__ __forceinline__ bf16x8 lds_read8(const short* p) {
    bf16x4 a = *(const bf16x4*)p;        // 8B-aligned ds_read_b64
    bf16x4 b = *(const bf16x4*)(p + 4);
    return __builtin_shufflevector(a, b, 0, 1, 2, 3, 4, 5, 6, 7);
}

// ---- fused filter ---------------------------------------------------------
// Block = 256 thr = 4 waves; wave: 32 queries (2 MFMA tiles); block: 128.
// acc init = bq (code col = cloc); e pre-scaled by -2 -> tt = acc[r].
__global__ __launch_bounds__(256, 4) void vq_filter(
        const float* __restrict__ z,
        const unsigned short* __restrict__ eh,
        const unsigned short* __restrict__ el,
        const float* __restrict__ bq, int* __restrict__ cnt,
        int* __restrict__ cand) {
    __shared__ __align__(16) short seh[CHUNK * ESTRIDE];
    __shared__ __align__(16) short sel[CHUNK * ESTRIDE];
    __shared__ float sbq[CHUNK];

    const int tid  = threadIdx.x;
    const int lane = tid & 63;
    const int wv   = tid >> 6;
    const int cloc = lane & 15, quad = lane >> 4;
    const int qbase = blockIdx.x * 128 + wv * 32;

    bf16x8 azh[2], azl[2];
#pragma unroll
    for (int t = 0; t < 2; ++t) {
        const int q  = qbase + t * 16 + cloc;
        const int b  = q >> 12;
        const int hw = q & 4095;
        const float* zb = z + ((size_t)b * EMB_DIM + quad * 8) * HW + hw;
#pragma unroll
        for (int k = 0; k < 8; ++k) {
            float v = zb[(size_t)k * HW];
            unsigned short hb = bf16_rne(v);
            float hf = __uint_as_float((unsigned)hb << 16);
            azh[t][k] = (short)hb;
            azl[t][k] = (short)bf16_rne(v - hf);
        }
    }

    float m1[2][4], m2[2][4];
    int   i1[2][4];
#pragma unroll
    for (int t = 0; t < 2; ++t)
#pragma unroll
        for (int r = 0; r < 4; ++r) {
            m1[t][r] = 3.4e38f; m2[t][r] = 3.4e38f; i1[t][r] = 0;
        }

    for (int ch = 0; ch < 4; ++ch) {
        if (ch) __syncthreads();
#pragma unroll
        for (int i = 0; i < 8; ++i) {
            const int chunk = i * 256 + tid;           // 0..2047
            const int r = chunk >> 3, c = chunk & 7;   // 8 x 4-short pieces
            *(uint2*)&seh[r * ESTRIDE + c * 4] =
                *(const uint2*)(eh + (size_t)(ch * CHUNK + r) * 32 + c * 4);
            *(uint2*)&sel[r * ESTRIDE + c * 4] =
                *(const uint2*)(el + (size_t)(ch * CHUNK + r) * 32 + c * 4);
        }
        sbq[tid] = bq[ch * CHUNK + tid];
        __syncthreads();

        for (int jt = 0; jt < 16; ++jt) {
            const int row = jt * 16 + cloc;
            bf16x8 efh = lds_read8(&seh[row * ESTRIDE + quad * 8]);
            bf16x8 efl = lds_read8(&sel[row * ESTRIDE + quad * 8]);
            const float bqv = sbq[row];
            const int jts = ch * 16 + jt;
#pragma unroll
            for (int t = 0; t < 2; ++t) {
                f32x4 acc = {bqv, bqv, bqv, bqv};
                acc = __builtin_amdgcn_mfma_f32_16x16x32_bf16(azl[t], efh, acc, 0, 0, 0);
                acc = __builtin_amdgcn_mfma_f32_16x16x32_bf16(azh[t], efl, acc, 0, 0, 0);
                acc = __builtin_amdgcn_mfma_f32_16x16x32_bf16(azh[t], efh, acc, 0, 0, 0);
#pragma unroll
                for (int r = 0; r < 4; ++r) {
                    const float tt = acc[r];
                    const bool l1 = tt < m1[t][r];
                    const bool l2 = tt < m2[t][r];
                    m2[t][r] = l1 ? m1[t][r] : (l2 ? tt : m2[t][r]);
                    m1[t][r] = l1 ? tt  : m1[t][r];
                    i1[t][r] = l1 ? jts : i1[t][r];
                }
            }
        }
    }

    float g[2][4];
#pragma unroll
    for (int t = 0; t < 2; ++t)
#pragma unroll
        for (int r = 0; r < 4; ++r) g[t][r] = m1[t][r];
#pragma unroll
    for (int off = 1; off < 16; off <<= 1)
#pragma unroll
        for (int t = 0; t < 2; ++t)
#pragma unroll
            for (int r = 0; r < 4; ++r)
                g[t][r] = fminf(g[t][r], __shfl_xor(g[t][r], off, 64));

#pragma unroll
    for (int t = 0; t < 2; ++t)
#pragma unroll
        for (int r = 0; r < 4; ++r) {
            const float thr = g[t][r] + MARGIN;
            const int q = qbase + t * 16 + quad * 4 + r;
            if (m1[t][r] <= thr) {
                int pos = atomicAdd(&cnt[q], 1);
                if (pos < 8) cand[(q << 3) + pos] = i1[t][r] * 16 + cloc;
            }
            if (m2[t][r] <= thr) atomicAdd(&cnt[q], 1000);  // overflow
        }
}

// ---- exact-rescore building blocks (verified numpy-fp32 chain) ------------
#define LOADZ(c) float z##c = zp[(size_t)(c) * HW];
#define Z_SQ_A()                                                              \
    float r0 = __fmul_rn(z0, z0), r1 = __fmul_rn(z1, z1);                     \
    float r2 = __fmul_rn(z2, z2), r3 = __fmul_rn(z3, z3);                     \
    float r4 = __fmul_rn(z4, z4), r5 = __fmul_rn(z5, z5);                     \
    float r6 = __fmul_rn(z6, z6), r7 = __fmul_rn(z7, z7);                     \
    r0 = __fadd_rn(r0, __fmul_rn(z8,  z8));  r0 = __fadd_rn(r0, __fmul_rn(z16, z16)); \
    r0 = __fadd_rn(r0, __fmul_rn(z24, z24));                                  \
    r1 = __fadd_rn(r1, __fmul_rn(z9,  z9));  r1 = __fadd_rn(r1, __fmul_rn(z17, z17)); \
    r1 = __fadd_rn(r1, __fmul_rn(z25, z25));                                  \
    r2 = __fadd_rn(r2, __fmul_rn(z10, z10)); r2 = __fadd_rn(r2, __fmul_rn(z18, z18)); \
    r2 = __fadd_rn(r2, __fmul_rn(z26, z26));                                  \
    r3 = __fadd_rn(r3, __fmul_rn(z11, z11)); r3 = __fadd_rn(r3, __fmul_rn(z19, z19)); \
    r3 = __fadd_rn(r3, __fmul_rn(z27, z27));                                  \
    r4 = __fadd_rn(r4, __fmul_rn(z12, z12)); r4 = __fadd_rn(r4, __fmul_rn(z20, z20)); \
    r4 = __fadd_rn(r4, __fmul_rn(z28, z28));                                  \
    r5 = __fadd_rn(r5, __fmul_rn(z13, z13)); r5 = __fadd_rn(r5, __fmul_rn(z21, z21)); \
    r5 = __fadd_rn(r5, __fmul_rn(z29, z29));                                  \
    r6 = __fadd_rn(r6, __fmul_rn(z14, z14)); r6 = __fadd_rn(r6, __fmul_rn(z22, z22)); \
    r6 = __fadd_rn(r6, __fmul_rn(z30, z30));                                  \
    r7 = __fadd_rn(r7, __fmul_rn(z15, z15)); r7 = __fadd_rn(r7, __fmul_rn(z23, z23)); \
    r7 = __fadd_rn(r7, __fmul_rn(z31, z31));                                  \
    const float a = __fadd_rn(                                                \
        __fadd_rn(__fadd_rn(r0, r1), __fadd_rn(r2, r3)),                      \
        __fadd_rn(__fadd_rn(r4, r5), __fadd_rn(r6, r7)));

#define FMA1(k) m = __fmaf_rn(z##k, e[(k)], m);
#define EXACT_KEY(jv)                                                         \
    {                                                                         \
        const float* e = emb + (size_t)(jv) * EMB_DIM;                        \
        float m = 0.0f;                                                       \
        REPEAT32(FMA1)                                                        \
        float d = __fsub_rn(__fadd_rn(a, bq[(jv)]), __fmul_rn(2.0f, m));      \
        unsigned u = __float_as_uint(d);                                      \
        u = (u & 0x80000000u) ? ~u : (u | 0x80000000u);                       \
        unsigned long long kk =                                               \
            ((unsigned long long)u << 32) | (unsigned)(jv);                   \
        if (kk < bestk) bestk = kk;                                           \
    }

// ---- pass3: cnt==1 shortcut; [2,8] exact rescore; else overflow list ------
__global__ __launch_bounds__(256, 2) void vq_pass3(
        const float* __restrict__ z, const float* __restrict__ emb,
        const float* __restrict__ bq, const int* __restrict__ cnt,
        const int* __restrict__ cand, int* __restrict__ ovfc,
        int* __restrict__ ovfl, float* __restrict__ out_zq,
        float* __restrict__ out_idx) {
    const int n  = blockIdx.x * 256 + threadIdx.x;
    const int b  = n >> 12;
    const int hw = n & 4095;
    const int c = cnt[n];
    if (c < 1 || c > 8) {                 // filter couldn't bound it
        int pos = atomicAdd(ovfc, 1);
        ovfl[pos] = n;                    // OVF_CAP == N_TOT, can't overflow
        return;
    }
    int bidx;
    if (c == 1) {
        // single in-margin candidate and no overflow -> it IS the argmin
        bidx = cand[n << 3];
    } else {
        const float* zp = z + (size_t)b * EMB_DIM * HW + hw;
        REPEAT32(LOADZ)
        Z_SQ_A()
        unsigned long long bestk = ~0ull;
        for (int i = 0; i < c; ++i) { const int jv = cand[(n << 3) + i]; EXACT_KEY(jv) }
        bidx = (int)(unsigned)(bestk & 0xffffffffu);
    }
    out_idx[n] = (float)bidx;
    const float* eb = emb + (size_t)bidx * EMB_DIM;
    float* op = out_zq + (size_t)b * EMB_DIM * HW + hw;
#pragma unroll
    for (int cc = 0; cc < EMB_DIM; ++cc) op[(size_t)cc * HW] = eb[cc];
}

// ---- fixup: block-per-query exact full scan (parallel over codes) ---------
__global__ __launch_bounds__(256) void vq_fixup(
        const float* __restrict__ z, const float* __restrict__ emb,
        const float* __restrict__ bq, const int* __restrict__ ovfc,
        const int* __restrict__ ovfl, float* __restrict__ out_zq,
        float* __restrict__ out_idx) {
    __shared__ unsigned long long bs[256];
    const int tid = threadIdx.x;
    int total = *ovfc;
    if (total > OVF_CAP) total = OVF_CAP;

    for (int it = blockIdx.x; it < total; it += gridDim.x) {
        const int n  = ovfl[it];
        const int b  = n >> 12;
        const int hw = n & 4095;
        const float* zp = z + (size_t)b * EMB_DIM * HW + hw;  // broadcast loads
        REPEAT32(LOADZ)
        Z_SQ_A()
        unsigned long long bestk = ~0ull;
#pragma unroll
        for (int k = 0; k < 4; ++k) { const int jv = tid * 4 + k; EXACT_KEY(jv) }
        bs[tid] = bestk;
        __syncthreads();
        for (int off = 128; off > 0; off >>= 1) {
            if (tid < off && bs[tid + off] < bs[tid]) bs[tid] = bs[tid + off];
            __syncthreads();
        }
        const int bidx = (int)(unsigned)(bs[0] & 0xffffffffu);
        if (tid == 0) out_idx[n] = (float)bidx;
        if (tid < EMB_DIM)
            out_zq[(size_t)b * EMB_DIM * HW + (size_t)tid * HW + hw] =
                emb[(size_t)bidx * EMB_DIM + tid];
        __syncthreads();
    }
}

// ================== proven R7/R5 exhaustive fallback =======================
#define SCAN_GROUP4(j)                                                        \
    {                                                                         \
        const float* e = emb + (size_t)(j) * EMB_DIM;                         \
        const float bq0 = bq[(j) + 0], bq1 = bq[(j) + 1];                     \
        const float bq2 = bq[(j) + 2], bq3 = bq[(j) + 3];                     \
        float m0 = 0.0f, m1 = 0.0f, m2 = 0.0f, m3 = 0.0f;                     \
        REPEAT32(FMA_K)                                                       \
        float d0 = __fsub_rn(__fadd_rn(a, bq0), __fmul_rn(2.0f, m0));         \
        float d1 = __fsub_rn(__fadd_rn(a, bq1), __fmul_rn(2.0f, m1));         \
        float d2 = __fsub_rn(__fadd_rn(a, bq2), __fmul_rn(2.0f, m2));         \
        float d3 = __fsub_rn(__fadd_rn(a, bq3), __fmul_rn(2.0f, m3));         \
        if (d0 < best) { best = d0; bidx = (j) + 0; }                         \
        if (d1 < best) { best = d1; bidx = (j) + 1; }                         \
        if (d2 < best) { best = d2; bidx = (j) + 2; }                         \
        if (d3 < best) { best = d3; bidx = (j) + 3; }                         \
    }
#define FMA_K(k) \
        m0 = __fmaf_rn(z##k, e[0 * EMB_DIM + (k)], m0); \
        m1 = __fmaf_rn(z##k, e[1 * EMB_DIM + (k)], m1); \
        m2 = __fmaf_rn(z##k, e[2 * EMB_DIM + (k)], m2); \
        m3 = __fmaf_rn(z##k, e[3 * EMB_DIM + (k)], m3);

__global__ __launch_bounds__(256) void vq_sqnorm_kernel(
        const float* __restrict__ emb, float* __restrict__ bq) {
    int j = blockIdx.x * 256 + threadIdx.x;
    if (j < NUM_EMB) bq[j] = pairwise_sq32(emb + j * EMB_DIM);
}

__global__ __launch_bounds__(128, 4) void vq_partial_kernel(
        const float* __restrict__ z, const float* __restrict__ emb,
        const float* __restrict__ bq, unsigned long long* __restrict__ pk) {
    const int n  = blockIdx.x * 128 + threadIdx.x;
    const int b  = n >> 12;
    const int hw = n & 4095;
    const float* zp = z + (size_t)b * EMB_DIM * HW + hw;
    REPEAT32(LOADZ)
    Z_SQ_A()
    const int j0 = blockIdx.y * CODES_PER;
    float best = 3.4e38f;
    int   bidx = j0;
    for (int j = j0; j < j0 + CODES_PER; j += 4) SCAN_GROUP4(j)
    pk[(size_t)blockIdx.y * N_TOT + n] =
        ((unsigned long long)__float_as_uint(best) << 32) | (unsigned)bidx;
}

__global__ __launch_bounds__(256, 2) void vq_main_kernel(
        const float* __restrict__ z, const float* __restrict__ emb,
        const float* __restrict__ bq, float* __restrict__ out_zq,
        float* __restrict__ out_idx) {
    const int n  = blockIdx.x * 256 + threadIdx.x;
    const int b  = n >> 12;
    const int hw = n & 4095;
    const float* zp = z + (size_t)b * EMB_DIM * HW + hw;
    REPEAT32(LOADZ)
    Z_SQ_A()
    float best = 3.4e38f;
    int   bidx = 0;
    for (int j = 0; j < NUM_EMB; j += 4) SCAN_GROUP4(j)
    out_idx[n] = (float)bidx;
    const float* eb = emb + (size_t)bidx * EMB_DIM;
    float* op = out_zq + (size_t)b * EMB_DIM * HW + hw;
#pragma unroll
    for (int cc = 0; cc < EMB_DIM; ++cc) op[(size_t)cc * HW] = eb[cc];
}

__global__ __launch_bounds__(256) void vq_combine_kernel(
        const float* __restrict__ emb,
        const unsigned long long* __restrict__ pk,
        float* __restrict__ out_zq, float* __restrict__ out_idx) {
    const int n = blockIdx.x * 256 + threadIdx.x;
    unsigned long long m = pk[n];
#pragma unroll
    for (int y = 1; y < NSPLIT; ++y) {
        unsigned long long v = pk[(size_t)y * N_TOT + n];
        if (v < m) m = v;
    }
    const int bidx = (int)(unsigned)(m & 0xffffffffu);
    out_idx[n] = (float)bidx;
    const int b  = n >> 12;
    const int hw = n & 4095;
    const float* eb = emb + (size_t)bidx * EMB_DIM;
    float* op = out_zq + (size_t)b * EMB_DIM * HW + hw;
#pragma unroll
    for (int cc = 0; cc < EMB_DIM; ++cc) op[(size_t)cc * HW] = eb[cc];
}

extern "C" void kernel_launch(void* const* d_in, const int* in_sizes, int n_in,
                              void* d_out, int out_size, void* d_ws,
                              size_t ws_size, hipStream_t stream) {
    const float* z   = (const float*)d_in[0];
    const float* emb = (const float*)d_in[1];
    char* ws = (char*)d_ws;
    float* out0 = (float*)d_out;
    float* out1 = out0 + (size_t)BATCH * EMB_DIM * HW;

    if (ws_size >= WS_NEED) {
        float*          bq   = (float*)(ws + OFF_BQ);
        unsigned short* eh   = (unsigned short*)(ws + OFF_EH);
        unsigned short* el   = (unsigned short*)(ws + OFF_EL);
        int*            cnt  = (int*)(ws + OFF_CNT);
        int*            cand = (int*)(ws + OFF_CAND);
        int*            ovfc = (int*)(ws + OFF_OVFC);
        int*            ovfl = (int*)(ws + OFF_OVFL);

        vq_prep_e<<<N_TOT / 256, 256, 0, stream>>>(emb, bq, eh, el, cnt, ovfc);
        vq_filter<<<N_TOT / 128, 256, 0, stream>>>(z, eh, el, bq, cnt, cand);
        vq_pass3<<<N_TOT / 256, 256, 0, stream>>>(z, emb, bq, cnt, cand,
                                                  ovfc, ovfl, out0, out1);
        vq_fixup<<<1024, 256, 0, stream>>>(z, emb, bq, ovfc, ovfl,
                                           out0, out1);
    } else if (ws_size >= WS_NEED_R7) {
        float* bq = (float*)ws;
        unsigned long long* pk = (unsigned long long*)(ws + 4096);
        vq_sqnorm_kernel<<<NUM_EMB / 256, 256, 0, stream>>>(emb, bq);
        vq_partial_kernel<<<dim3(N_TOT / 128, NSPLIT), 128, 0, stream>>>(
            z, emb, bq, pk);
        vq_combine_kernel<<<N_TOT / 256, 256, 0, stream>>>(emb, pk, out0, out1);
    } else {
        float* bq = (float*)ws;
        vq_sqnorm_kernel<<<NUM_EMB / 256, 256, 0, stream>>>(emb, bq);
        vq_main_kernel<<<N_TOT / 256, 256, 0, stream>>>(z, emb, bq, out0, out1);
    }
}